// Round 3
// baseline (327.345 us; speedup 1.0000x reference)
//
#include <hip/hip_runtime.h>
#include <hip/hip_bf16.h>
#include <stdint.h>

#define B_N   16384
#define L_N   63
#define K2LOG2E 2.8853900817779268f   // 2*log2(e)
#define LOG2E   1.4426950408889634f

typedef unsigned int   u32;
typedef unsigned short u16;
typedef __attribute__((ext_vector_type(8))) __bf16 bf16x8;
typedef __attribute__((ext_vector_type(4))) float  f32x4;

__device__ __forceinline__ u16 f2b(float f){
  u32 u = __builtin_bit_cast(u32, f);
  u += 0x7fffu + ((u >> 16) & 1u);
  return (u16)(u >> 16);
}
__device__ __forceinline__ u32 pk_bf16(float lo, float hi){
  u32 r;
  asm("v_cvt_pk_bf16_f32 %0, %1, %2" : "=v"(r) : "v"(lo), "v"(hi));
  return r;
}
// tanh(a) = 1 - 2/(exp2(a*2log2e)+1); 5 VALU ops, saturation-safe
__device__ __forceinline__ float tanh_pre(float a){
  float t = __builtin_amdgcn_exp2f(a * K2LOG2E);
  float r = __builtin_amdgcn_rcpf(t + 1.0f);
  return fmaf(-2.0f, r, 1.0f);
}

// ---- W1[l][d][n] (masked d<=l) -> W1T[l][n][64], col 63 = b1 (bias) ----
__global__ void k_conv_w1(const float* __restrict__ W1, const float* __restrict__ b1,
                          u16* __restrict__ out){
  __shared__ u16 t[128*64];
  const int l = blockIdx.x, tid = threadIdx.x;
  #pragma unroll
  for (int i = 0; i < 32; ++i) t[i*256 + tid] = 0;
  __syncthreads();
  for (int i = 0; i < 32; ++i){
    int idx = i*256 + tid;              // idx = d*128 + n (coalesced read)
    if (idx < 63*128){
      int d = idx >> 7, n = idx & 127;
      if (d <= l) t[n*64 + d] = f2b(W1[(l*63 + d)*128 + n]);
    }
  }
  if (tid < 128) t[tid*64 + 63] = f2b(b1[l*128 + tid]);   // bias column (x[:,63]=1)
  __syncthreads();
  uint4* o = (uint4*)(out + l*(128*64));
  const uint4* s4 = (const uint4*)t;
  #pragma unroll
  for (int i = 0; i < 4; ++i) o[i*256 + tid] = s4[i*256 + tid];
}

// ---- W2[l][h][n] -> W2T_ext[l][n][160]: cols 0..127 = W2^T, col 128 = b2, rest 0 ----
__global__ void k_conv_w2(const float* __restrict__ W2, const float* __restrict__ b2,
                          u16* __restrict__ out){
  __shared__ u16 t[128*160];
  const int l = blockIdx.x, tid = threadIdx.x;
  #pragma unroll
  for (int i = 0; i < 80; ++i) t[i*256 + tid] = 0;
  __syncthreads();
  #pragma unroll
  for (int i = 0; i < 64; ++i){
    int idx = i*256 + tid;              // idx = h*128 + n (coalesced read)
    int h = idx >> 7, n = idx & 127;
    t[n*160 + h] = f2b(W2[l*16384 + idx]);
  }
  if (tid < 128) t[tid*160 + 128] = f2b(b2[l*128 + tid]); // bias slice
  __syncthreads();
  uint4* o = (uint4*)(out + l*(128*160));
  const uint4* s4 = (const uint4*)t;
  #pragma unroll
  for (int i = 0; i < 10; ++i) o[i*256 + tid] = s4[i*256 + tid];
}

// ---- W3[l][n][2] -> W3T[l][16][128]: rows 0,1 = W3^T, rows 2..15 = 0 ----
__global__ void k_conv_w3(const float* __restrict__ W3, u16* __restrict__ out){
  __shared__ u16 t[16*128];
  const int l = blockIdx.x, tid = threadIdx.x;
  #pragma unroll
  for (int i = 0; i < 8; ++i) t[i*256 + tid] = 0;
  __syncthreads();
  if (tid < 128){
    t[tid]       = f2b(W3[l*256 + tid*2 + 0]);
    t[128 + tid] = f2b(W3[l*256 + tid*2 + 1]);
  }
  __syncthreads();
  uint4* o = (uint4*)(out + l*(16*128));
  o[tid] = ((const uint4*)t)[tid];
}

// ---- x f32 -> bf16, with column 63 forced to 1.0 (bias lane for stage 1) ----
__global__ void k_conv_x(const float* __restrict__ x, u16* __restrict__ out){
  int idx = blockIdx.x*256 + threadIdx.x;     // B_N*64/4 chunks
  float4 v = ((const float4*)x)[idx];
  ushort4 r;
  r.x = f2b(v.x); r.y = f2b(v.y); r.z = f2b(v.z);
  r.w = ((idx & 15) == 15) ? (u16)0x3F80 : f2b(v.w);
  ((ushort4*)out)[idx] = r;
}

// ---- init: z[:,63] (d=0 term) and logdet base = -a0 ----
__global__ void k_init(const float* __restrict__ x, const float* __restrict__ ip,
                       float* __restrict__ out){
  int row = blockIdx.x*256 + threadIdx.x;
  float z = (x[(size_t)row*64] - ip[0]) * __builtin_amdgcn_exp2f(-ip[1]*LOG2E);
  out[(size_t)row*64 + 63] = z;
  out[(size_t)B_N*64 + row] = -ip[1];
}

// ---- main: one WAVE = 16 batch rows x one layer; all 128 h per wave.
// No __syncthreads. Per-wave 4KB LDS scratch [16 b][128 h] bf16, 16B-chunk
// XOR swizzle (<=2-way banks). Biases via MFMA (W1T col63, W2T slice 4).
__global__ __launch_bounds__(256, 4)
void k_main(const u16* __restrict__ W1T, const u16* __restrict__ W2T,
            const u16* __restrict__ W3T, const u16* __restrict__ xbf,
            const float* __restrict__ x, const float* __restrict__ b3,
            float* __restrict__ out)
{
  __shared__ __align__(16) char lds[16384];
  const int tid = threadIdx.x;
  const int l  = blockIdx.y;
  const int wv = tid >> 6;
  const int ln = tid & 63;
  const int c  = ln & 15;       // batch column within wave / fragment col
  const int g  = ln >> 4;       // k-group
  const int rowbase = blockIdx.x*64 + wv*16;

  char* const my  = lds + wv*4096 + c*256;   // this lane's batch row in scratch
  const int swz = c & 7;

  // ---- stage 1: h1[128][16b] = tanh(W1T . x^T)  (bias in k=63) ----
  const u16* xrow = xbf + (size_t)(rowbase + c)*64;
  bf16x8 xf0 = *(const bf16x8*)(xrow + g*8);
  bf16x8 xf1 = *(const bf16x8*)(xrow + 32 + g*8);

  const u16* w1p = W1T + l*(128*64);
  f32x4 acc1[8] = {};
  #pragma unroll
  for (int mt = 0; mt < 8; ++mt){
    const u16* ap = w1p + (mt*16 + c)*64 + g*8;
    bf16x8 a0 = *(const bf16x8*)(ap);
    bf16x8 a1 = *(const bf16x8*)(ap + 32);
    acc1[mt] = __builtin_amdgcn_mfma_f32_16x16x32_bf16(a0, xf0, acc1[mt], 0,0,0);
    acc1[mt] = __builtin_amdgcn_mfma_f32_16x16x32_bf16(a1, xf1, acc1[mt], 0,0,0);
  }

  // epilogue 1: tanh, pack, scatter to [b][h] scratch (same-wave: no barrier)
  #pragma unroll
  for (int mt = 0; mt < 8; ++mt){
    u32 p0 = pk_bf16(tanh_pre(acc1[mt][0]), tanh_pre(acc1[mt][1]));
    u32 p1 = pk_bf16(tanh_pre(acc1[mt][2]), tanh_pre(acc1[mt][3]));
    int chunk = (mt*2 + (g>>1)) ^ swz;
    *(uint2*)(my + chunk*16 + (g&1)*8) = make_uint2(p0, p1);
  }

  // ---- stage 2: h2 = tanh(W2T_ext . [h1;e0])  (bias in k=128) ----
  bf16x8 hf[4];
  #pragma unroll
  for (int s = 0; s < 4; ++s)
    hf[s] = *(const bf16x8*)(my + (((s*4 + g) ^ swz) << 4));
  uint4 cw; cw.x = (g == 0) ? 0x00003F80u : 0u; cw.y = cw.z = cw.w = 0u;
  bf16x8 cf = __builtin_bit_cast(bf16x8, cw);

  const u16* w2p = W2T + l*(128*160);
  f32x4 acc2[8] = {};
  #pragma unroll
  for (int mt = 0; mt < 8; ++mt){
    const u16* ap = w2p + (mt*16 + c)*160 + g*8;
    #pragma unroll
    for (int s = 0; s < 4; ++s){
      bf16x8 a = *(const bf16x8*)(ap + s*32);
      acc2[mt] = __builtin_amdgcn_mfma_f32_16x16x32_bf16(a, hf[s], acc2[mt], 0,0,0);
    }
    bf16x8 ab = *(const bf16x8*)(ap + 128);
    acc2[mt] = __builtin_amdgcn_mfma_f32_16x16x32_bf16(ab, cf, acc2[mt], 0,0,0);
  }

  // epilogue 2: tanh, pack, rewrite scratch with h2
  #pragma unroll
  for (int mt = 0; mt < 8; ++mt){
    u32 p0 = pk_bf16(tanh_pre(acc2[mt][0]), tanh_pre(acc2[mt][1]));
    u32 p1 = pk_bf16(tanh_pre(acc2[mt][2]), tanh_pre(acc2[mt][3]));
    int chunk = (mt*2 + (g>>1)) ^ swz;
    *(uint2*)(my + chunk*16 + (g&1)*8) = make_uint2(p0, p1);
  }

  // ---- stage 3: [mu;alpha][16b] = W3T . h2 via one MFMA chain ----
  const u16* w3p = W3T + l*(16*128);
  f32x4 acc3 = {};
  #pragma unroll
  for (int s = 0; s < 4; ++s){
    bf16x8 hb = *(const bf16x8*)(my + (((s*4 + g) ^ swz) << 4));
    bf16x8 a  = *(const bf16x8*)(w3p + c*128 + s*32 + g*8);
    acc3 = __builtin_amdgcn_mfma_f32_16x16x32_bf16(a, hb, acc3, 0,0,0);
  }

  // ---- finalize: z + logdet contribution (rows 0,1 live in g==0 lanes) ----
  if (g == 0){
    int row = rowbase + c;
    float muv = acc3[0] + b3[l*2 + 0];
    float alv = acc3[1] + b3[l*2 + 1];
    float xv  = x[(size_t)row*64 + (l + 1)];
    float z   = (xv - muv) * __builtin_amdgcn_exp2f(-alv * LOG2E);
    out[(size_t)row*64 + (62 - l)] = z;
    atomicAdd(out + (size_t)B_N*64 + row, -alv);
  }
}

extern "C" void kernel_launch(void* const* d_in, const int* in_sizes, int n_in,
                              void* d_out, int out_size, void* d_ws, size_t ws_size,
                              hipStream_t stream)
{
  const float* x  = (const float*)d_in[0];
  const float* W1 = (const float*)d_in[1];
  const float* b1 = (const float*)d_in[2];
  const float* W2 = (const float*)d_in[3];
  const float* b2 = (const float*)d_in[4];
  const float* W3 = (const float*)d_in[5];
  const float* b3 = (const float*)d_in[6];
  const float* ip = (const float*)d_in[7];

  char* ws = (char*)d_ws;
  // w1t 1.03MB | w2t_ext 2.58MB | w3t 0.26MB | xbf 2MB  = ~5.9MB
  u16* w1t = (u16*)(ws);
  u16* w2t = (u16*)(ws + 1048576);
  u16* w3t = (u16*)(ws + 3670016);
  u16* xbf = (u16*)(ws + 3932160);
  if (ws_size < 6029312) return;  // fail visibly rather than corrupt

  k_conv_w1<<<L_N, 256, 0, stream>>>(W1, b1, w1t);
  k_conv_w2<<<L_N, 256, 0, stream>>>(W2, b2, w2t);
  k_conv_w3<<<L_N, 256, 0, stream>>>(W3, w3t);
  k_conv_x<<<(B_N*64/4)/256, 256, 0, stream>>>(x, xbf);
  k_init<<<B_N/256, 256, 0, stream>>>(x, ip, (float*)d_out);

  dim3 grid(B_N/64, L_N);
  k_main<<<grid, 256, 0, stream>>>(w1t, w2t, w3t, xbf, x, b3, (float*)d_out);
}